// Round 7
// baseline (702.895 us; speedup 1.0000x reference)
//
#include <hip/hip_runtime.h>

// ---------------------------------------------------------------------------
// SharedPPOSoftModularizedMLP on MI355X (gfx950)
// B=8192, OBS=128, TASK=64, D=1024, E=8, L=4
// bf16 MFMA (16x16x32), fp32 accumulate.
// R15 == R14 resubmit (R14 bench died on container acquisition, no data):
//   (a) expert-stage chunk 8192 -> 2048: he/xx/eWt working set (33+33+32 MB)
//       becomes Infinity-Cache-resident -- mix / GEMM2-A / mix_head reads
//       come from L3 instead of HBM round-trips;
//   (b) routing split-K de-atomic'd: k-chunk bz stores its partial to plane
//       bz (4 planes/layer); mk_pbf and softmax8 sum the planes;
//   (c) prep drops pbuf zeroing + dead out-bias init (grid 28288->23904).
//   gemm_n256 / gemm_main / mix / mix_head unchanged (R13-verified).
// ---------------------------------------------------------------------------

typedef __attribute__((ext_vector_type(8))) short short8;   // 8 x bf16 frag
typedef __attribute__((ext_vector_type(4))) float floatx4;  // MFMA acc
typedef unsigned short us;

__device__ __forceinline__ us f2bf(float f) {
  union { float f; unsigned u; } v; v.f = f;
  return (us)((v.u + 0x7FFFu + ((v.u >> 16) & 1u)) >> 16);  // RNE
}
__device__ __forceinline__ float bf2f(us h) {
  union { unsigned u; float f; } v; v.u = ((unsigned)h) << 16;
  return v.f;
}

// async global->LDS, 16B per lane; lds dest = wave-uniform base + lane*16
__device__ __forceinline__ void g2lds16(const void* g, void* l) {
  __builtin_amdgcn_global_load_lds(
      (const __attribute__((address_space(1))) void*)g,
      (__attribute__((address_space(3))) void*)l, 16, 0, 0);
}

// ---------------------------------------------------------------------------
// Main-path GEMM: C[M,N] = post(act(A@Bt^T + bias)); all bf16, M,N %128==0.
// post: MUL -> elementwise * Mul[M,N]; RELU2 -> relu after MUL.
// CB2: Cb = value, Cb2 = relu(value).
// grid=(N/128, M/128, E). XCD chunk swizzle when total blocks % 8 == 0.
// ---------------------------------------------------------------------------
template<bool BIAS, bool RELU, bool MUL, bool RELU2, bool CB2>
__global__ __launch_bounds__(256)
void gemm_main(const us* __restrict__ A, const us* __restrict__ Bt,
               const float* __restrict__ bias,
               us* __restrict__ Cb, us* __restrict__ Cb2,
               const us* __restrict__ Mul,
               int N, int K, int lda, int ldb,
               long long sA, long long sB, long long sBias, long long sC)
{
  // ---- XCD chunk swizzle ----
  int bx = blockIdx.x, by = blockIdx.y, bz = blockIdx.z;
  {
    const int gx = gridDim.x, gy = gridDim.y;
    const int total = gx * gy * gridDim.z;
    if ((total & 7) == 0) {
      int L = bx + gx * (by + gy * bz);
      int per = total >> 3;
      int w = (L & 7) * per + (L >> 3);
      bx = w % gx; w /= gx;
      by = w % gy; bz = w / gy;
    }
  }

  const int e = bz;
  const us* Ab = A + (size_t)e * sA;
  const us* Bb = Bt + (size_t)e * sB;

  const int m0 = by * 128;
  const int n0 = bx * 128;
  const int tid = threadIdx.x;
  const int wave = tid >> 6;
  const int lane = tid & 63;
  const int wm = (wave >> 1) * 64;
  const int wn = (wave & 1) * 64;
  const int lr = lane & 15;
  const int lq = lane >> 4;

  // staging: A = smem[0..8191], B = smem[8192..16383]  (us units)
  // epilogue tile: smem[0..17407] as [128][136] us  (R4 layout)
  __shared__ __align__(16) us smem[128 * 136 + 64];
  us* ldsA = smem;
  us* ldsB = smem + 128 * 64;

  floatx4 acc[4][4];
#pragma unroll
  for (int i = 0; i < 4; ++i)
#pragma unroll
    for (int j = 0; j < 4; ++j) acc[i][j] = (floatx4){0.f, 0.f, 0.f, 0.f};

  for (int k0 = 0; k0 < K; k0 += 64) {
#pragma unroll
    for (int c = 0; c < 4; ++c) {
      int slot = c * 256 + tid;               // physical 16B chunk
      int r = slot >> 3;
      int s = (slot & 7) ^ (r & 7);           // logical slab (XOR swizzle)
      int ubase = (c * 256 + wave * 64) * 8;  // wave-uniform LDS base (us)
      g2lds16(Ab + (size_t)(m0 + r) * lda + k0 + s * 8, ldsA + ubase);
      g2lds16(Bb + (size_t)(n0 + r) * ldb + k0 + s * 8, ldsB + ubase);
    }
    __syncthreads();

#pragma unroll
    for (int kk = 0; kk < 2; ++kk) {
      short8 af[4], bfr[4];
#pragma unroll
      for (int t = 0; t < 4; ++t) {
        int m = wm + t * 16 + lr;
        int s = kk * 4 + lq;
        af[t]  = *(const short8*)(ldsA + (size_t)(m * 8 + (s ^ (m & 7))) * 8);
        int n = wn + t * 16 + lr;
        bfr[t] = *(const short8*)(ldsB + (size_t)(n * 8 + (s ^ (n & 7))) * 8);
      }
#pragma unroll
      for (int mt = 0; mt < 4; ++mt)
#pragma unroll
        for (int nt = 0; nt < 4; ++nt)
          acc[mt][nt] = __builtin_amdgcn_mfma_f32_16x16x32_bf16(
              af[mt], bfr[nt], acc[mt][nt], 0, 0, 0);
    }
    __syncthreads();
  }

  // ---- epilogue (R4): stage bf16 tile in LDS [128][136], store dwordx4 ----
  // C/D layout: col = lane&15, row = lq*4 + r
#pragma unroll
  for (int nt = 0; nt < 4; ++nt) {
    int coll = wn + nt * 16 + lr;
    int col = n0 + coll;
    float bv = BIAS ? bias[(size_t)e * sBias + col] : 0.f;
#pragma unroll
    for (int mt = 0; mt < 4; ++mt) {
      int rowb = wm + mt * 16 + lq * 4;
#pragma unroll
      for (int r = 0; r < 4; ++r) {
        int rowl = rowb + r;
        float v = acc[mt][nt][r] + bv;
        if (RELU) v = fmaxf(v, 0.f);
        if (MUL) v *= bf2f(Mul[(size_t)(m0 + rowl) * N + col]);
        if (RELU2) v = fmaxf(v, 0.f);
        smem[rowl * 136 + coll] = f2bf(v);
      }
    }
  }
  __syncthreads();
#pragma unroll
  for (int c = 0; c < 8; ++c) {
    int sl = c * 256 + tid;
    int rowl = sl >> 4;
    int seg = sl & 15;
    short8 val = *(const short8*)(smem + rowl * 136 + seg * 8);
    size_t gidx = (size_t)e * sC + (size_t)(m0 + rowl) * N + n0 + seg * 8;
    *(short8*)(Cb + gidx) = val;
    if (CB2) {
      short8 rl;
#pragma unroll
      for (int q = 0; q < 8; ++q) {
        us u = (us)val[q];
        rl[q] = (short)((u & 0x8000u) ? (us)0 : u);
      }
      *(short8*)(Cb2 + gidx) = rl;
    }
  }
}

// ---------------------------------------------------------------------------
// gemm_n256: deep-pipelined 256x256-tile GEMM (R10/R13 verified: MfmaUtil 36,
// 0 bank conflicts; 851 TF = m248 grouped mark for this shape).
//   C[M,N] = relu?(A@Bt^T + bias), bf16 in/out, fp32 acc.
//   Requirements: M%256==0, N%256==0, K%32==0, K>=128.
//   grid = (N/256, M/256, E), block = 512 (8 waves, 2M x 4N).
// ---------------------------------------------------------------------------
template<bool BIAS, bool RELU>
__global__ __launch_bounds__(512, 2)
void gemm_n256(const us* __restrict__ A, const us* __restrict__ Bt,
               const float* __restrict__ bias, us* __restrict__ Cb,
               int N, int K, int lda, int ldb,
               long long sA, long long sB, long long sBias, long long sC)
{
  // ---- XCD chunk swizzle (grid here is always %8==0) ----
  int bx = blockIdx.x, by = blockIdx.y, bz = blockIdx.z;
  {
    const int gx = gridDim.x, gy = gridDim.y;
    const int total = gx * gy * gridDim.z;
    if ((total & 7) == 0) {
      int L = bx + gx * (by + gy * bz);
      int per = total >> 3;
      int w = (L & 7) * per + (L >> 3);
      bx = w % gx; w /= gx;
      by = w % gy; bz = w / gy;
    }
  }
  const int e = bz;
  const us* Ab = A + (size_t)e * sA;
  const us* Bb = Bt + (size_t)e * sB;

  const int m0 = by * 256;
  const int n0 = bx * 256;
  const int tid  = threadIdx.x;
  const int wave = tid >> 6;
  const int lane = tid & 63;
  const int wm = (wave >> 2) * 128;   // 2 M-waves x 128 rows
  const int wn = (wave & 3) * 64;     // 4 N-waves x 64 cols
  const int lr = lane & 15;
  const int lq = lane >> 4;

  // LDS ring: A subs at [0 .. 32767], B subs at [32768 .. 65535] (us units).
  // Each sub = 256 rows x 32 K bf16 = 8192 us.  Within a sub, element
  // (row, slab) [slab = 8-bf16 16B unit, 0..3] lives in 128B line
  // L = row>>1 at position p = (slab | ((row&1)<<2)) ^ (L&7).
  __shared__ __align__(16) us smem[65536];

  floatx4 acc[8][4];
#pragma unroll
  for (int i = 0; i < 8; ++i)
#pragma unroll
    for (int j = 0; j < 4; ++j) acc[i][j] = (floatx4){0.f, 0.f, 0.f, 0.f};

  // ---- per-thread staging constants (2 A-loads + 2 B-loads per sub) ----
  const us* srcA[2];
  const us* srcB[2];
#pragma unroll
  for (int i = 0; i < 2; ++i) {
    int c   = i * 512 + tid;        // physical 16B chunk 0..1023
    int Ln  = c >> 3;               // 128B line
    int pos = c & 7;
    int q   = pos ^ (Ln & 7);
    int row = 2 * Ln + (q >> 2);    // logical row 0..255
    int so  = (q & 3) * 8;          // logical slab offset (us)
    srcA[i] = Ab + (size_t)(m0 + row) * lda + so;
    srcB[i] = Bb + (size_t)(n0 + row) * ldb + so;
  }
  const int dst0 = wave * 512;      // wave-uniform LDS chunk base (us)

  // ---- per-lane fragment read offsets (constant across phases) ----
  int offA[8], offB[4];
#pragma unroll
  for (int t = 0; t < 8; ++t) {
    int m  = wm + t * 16 + lr;
    int Ln = m >> 1;
    offA[t] = Ln * 64 + (((lq | ((m & 1) << 2)) ^ (Ln & 7)) << 3);
  }
#pragma unroll
  for (int t = 0; t < 4; ++t) {
    int n  = wn + t * 16 + lr;
    int Ln = n >> 1;
    offB[t] = Ln * 64 + (((lq | ((n & 1) << 2)) ^ (Ln & 7)) << 3);
  }

  auto stage = [&](int s) {
    us* a = smem + (s & 3) * 8192;
    us* b = smem + 32768 + (s & 3) * 8192;
    const int ko = s << 5;          // global k offset (elements)
#pragma unroll
    for (int i = 0; i < 2; ++i) g2lds16(srcA[i] + ko, a + dst0 + i * 4096);
#pragma unroll
    for (int i = 0; i < 2; ++i) g2lds16(srcB[i] + ko, b + dst0 + i * 4096);
  };

  auto compute = [&](int bufi) {
    const us* a = smem + bufi * 8192;
    const us* b = smem + 32768 + bufi * 8192;
    short8 af[8], bfr[4];
#pragma unroll
    for (int t = 0; t < 4; ++t) bfr[t] = *(const short8*)(b + offB[t]);
#pragma unroll
    for (int t = 0; t < 8; ++t) af[t] = *(const short8*)(a + offA[t]);
    __builtin_amdgcn_s_setprio(1);
#pragma unroll
    for (int mt = 0; mt < 8; ++mt)
#pragma unroll
      for (int nt = 0; nt < 4; ++nt)
        acc[mt][nt] = __builtin_amdgcn_mfma_f32_16x16x32_bf16(
            af[mt], bfr[nt], acc[mt][nt], 0, 0, 0);
    __builtin_amdgcn_s_setprio(0);
  };

  // ---- prologue: 3 sub-tiles in flight ----
  stage(0); stage(1); stage(2);

  const int NP = K >> 5;            // phases (>=4 by contract)
  for (int p = 0; p < NP - 3; ++p) {
    asm volatile("s_waitcnt vmcnt(8)" ::: "memory");
    __builtin_amdgcn_s_barrier();
    __builtin_amdgcn_sched_barrier(0);
    stage(p + 3);
    compute(p & 3);
  }
  // ---- tail: drain 8 -> 4 -> 0 ----
  asm volatile("s_waitcnt vmcnt(8)" ::: "memory");
  __builtin_amdgcn_s_barrier();
  __builtin_amdgcn_sched_barrier(0);
  compute((NP - 3) & 3);
  asm volatile("s_waitcnt vmcnt(4)" ::: "memory");
  __builtin_amdgcn_s_barrier();
  __builtin_amdgcn_sched_barrier(0);
  compute((NP - 2) & 3);
  asm volatile("s_waitcnt vmcnt(0)" ::: "memory");
  __builtin_amdgcn_s_barrier();
  __builtin_amdgcn_sched_barrier(0);
  compute((NP - 1) & 3);

  // ---- epilogue: bias+relu, bf16 via swizzled LDS [256][256], 16B stores --
  __syncthreads();
#pragma unroll
  for (int nt = 0; nt < 4; ++nt) {
    int coll = wn + nt * 16 + lr;
    float bv = BIAS ? bias[(size_t)e * sBias + n0 + coll] : 0.f;
#pragma unroll
    for (int mt = 0; mt < 8; ++mt) {
      int rowb = wm + mt * 16 + lq * 4;
#pragma unroll
      for (int r = 0; r < 4; ++r) {
        int row = rowb + r;
        float v = acc[mt][nt][r] + bv;
        if (RELU) v = fmaxf(v, 0.f);
        smem[row * 256 + (coll ^ (((row >> 2) & 3) << 4))] = f2bf(v);
      }
    }
  }
  __syncthreads();
#pragma unroll
  for (int c = 0; c < 16; ++c) {
    int sl  = c * 512 + tid;
    int row = sl >> 5;
    int ch  = sl & 31;
    short8 val = *(const short8*)(smem + row * 256 +
                                  ((ch * 8) ^ (((row >> 2) & 3) << 4)));
    *(short8*)(Cb + (size_t)e * sC + (size_t)(m0 + row) * N + n0 + ch * 8) = val;
  }
}

// ---------------------------------------------------------------------------
// Split-K GEMM, non-atomic: k-chunk bz writes its fp32 partial to plane bz of
// Cf (plane = M*N floats, M = gridDim.y*128).  Consumers sum the planes.
// N may be < 128 (B-row clamp).  Used for routing p0/p1 (N=64, 4 k-chunks).
// ---------------------------------------------------------------------------
__global__ __launch_bounds__(256)
void gemm_splitk(const us* __restrict__ A, const us* __restrict__ Bt,
                 float* __restrict__ Cf,
                 int N, int K, int lda, int ldb,
                 long long sA, long long sB)
{
  int bx = blockIdx.x, by = blockIdx.y, bz = blockIdx.z;
  {
    const int gx = gridDim.x, gy = gridDim.y;
    const int total = gx * gy * gridDim.z;
    if ((total & 7) == 0) {
      int L = bx + gx * (by + gy * bz);
      int per = total >> 3;
      int w = (L & 7) * per + (L >> 3);
      bx = w % gx; w /= gx;
      by = w % gy; bz = w / gy;
    }
  }

  const us* Ab = A + (size_t)bz * sA;
  const us* Bb = Bt + (size_t)bz * sB;
  float* Cp = Cf + (size_t)bz * (size_t)gridDim.y * 128 * N;  // plane bz

  const int m0 = by * 128;
  const int n0 = bx * 128;
  const int tid = threadIdx.x;
  const int wave = tid >> 6;
  const int lane = tid & 63;
  const int wm = (wave >> 1) * 64;
  const int wn = (wave & 1) * 64;
  const int lr = lane & 15;
  const int lq = lane >> 4;

  __shared__ __align__(16) us smem[128 * 128];
  us* ldsA = smem;
  us* ldsB = smem + 128 * 64;

  floatx4 acc[4][4];
#pragma unroll
  for (int i = 0; i < 4; ++i)
#pragma unroll
    for (int j = 0; j < 4; ++j) acc[i][j] = (floatx4){0.f, 0.f, 0.f, 0.f};

  for (int k0 = 0; k0 < K; k0 += 64) {
#pragma unroll
    for (int c = 0; c < 4; ++c) {
      int slot = c * 256 + tid;
      int r = slot >> 3;
      int s = (slot & 7) ^ (r & 7);
      int ubase = (c * 256 + wave * 64) * 8;
      g2lds16(Ab + (size_t)(m0 + r) * lda + k0 + s * 8, ldsA + ubase);
      int nrow = n0 + r; if (nrow > N - 1) nrow = N - 1;  // clamp (N<128)
      g2lds16(Bb + (size_t)nrow * ldb + k0 + s * 8, ldsB + ubase);
    }
    __syncthreads();

#pragma unroll
    for (int kk = 0; kk < 2; ++kk) {
      short8 af[4], bfr[4];
#pragma unroll
      for (int t = 0; t < 4; ++t) {
        int m = wm + t * 16 + lr;
        int s = kk * 4 + lq;
        af[t]  = *(const short8*)(ldsA + (size_t)(m * 8 + (s ^ (m & 7))) * 8);
        int n = wn + t * 16 + lr;
        bfr[t] = *(const short8*)(ldsB + (size_t)(n * 8 + (s ^ (n & 7))) * 8);
      }
#pragma unroll
      for (int mt = 0; mt < 4; ++mt)
#pragma unroll
        for (int nt = 0; nt < 4; ++nt)
          acc[mt][nt] = __builtin_amdgcn_mfma_f32_16x16x32_bf16(
              af[mt], bfr[nt], acc[mt][nt], 0, 0, 0);
    }
    __syncthreads();
  }

#pragma unroll
  for (int nt = 0; nt < 4; ++nt) {
    int col = n0 + wn + nt * 16 + lr;
    if (col >= N) continue;
#pragma unroll
    for (int mt = 0; mt < 4; ++mt) {
      int row = m0 + wm + mt * 16 + lq * 4;
#pragma unroll
      for (int r = 0; r < 4; ++r)
        Cp[(size_t)(row + r) * N + col] = acc[mt][nt][r];
    }
  }
}

// ---------------------------------------------------------------------------
// Fused prep: all weight transposes (fp32 [R,C] -> bf16 [C,R]), Wh build,
// x split/convert.  One launch, range ladder.  (pbuf zeroing and out-bias
// init removed in R14: split-K planes are fully stored, mix_head writes out.)
// ---------------------------------------------------------------------------
__device__ __forceinline__ void transpose_tile(
    const float* __restrict__ in, us* __restrict__ out,
    int R, int C, int bx, int by, float (*tile)[33])
{
  const int tx = threadIdx.x & 31, ty = threadIdx.x >> 5;
  const int c0 = bx * 32, r0 = by * 32;
#pragma unroll
  for (int i = 0; i < 4; ++i) {
    int r = r0 + ty + i * 8, c = c0 + tx;
    tile[ty + i * 8][tx] = (r < R && c < C) ? in[(size_t)r * C + c] : 0.f;
  }
  __syncthreads();
#pragma unroll
  for (int i = 0; i < 4; ++i) {
    int c = c0 + ty + i * 8, r = r0 + tx;
    if (c < C && r < R) out[(size_t)c * R + r] = f2bf(tile[tx][ty + i * 8]);
  }
}

__global__ __launch_bounds__(256)
void prep_kernel(const float* __restrict__ x,
                 const float* __restrict__ sW1, const float* __restrict__ sW2,
                 const float* __restrict__ sW3, const float* __restrict__ tW,
                 const float* __restrict__ rdW, const float* __restrict__ ruW,
                 const float* __restrict__ eW,
                 const float* __restrict__ aW, const float* __restrict__ cW,
                 us* __restrict__ obs, us* __restrict__ task,
                 us* __restrict__ s1t, us* __restrict__ s2t,
                 us* __restrict__ s3t, us* __restrict__ tWt,
                 us* __restrict__ rdt, us* __restrict__ rut,
                 us* __restrict__ eWt, us* __restrict__ Wh)
{
  __shared__ float tile[32][33];
  int b = blockIdx.x;
  const int tid = threadIdx.x;

  if (b < 64)  { transpose_tile(sW1, s1t, 128, 512, b % 16, b / 16, tile); return; }
  b -= 64;
  if (b < 256) { transpose_tile(sW2, s2t, 512, 512, b % 16, b / 16, tile); return; }
  b -= 256;
  if (b < 512) { transpose_tile(sW3, s3t, 512, 1024, b % 32, b / 32, tile); return; }
  b -= 512;
  if (b < 64)  { transpose_tile(tW, tWt, 64, 1024, b % 32, b / 32, tile); return; }
  b -= 64;
  if (b < 128) { int l = b >> 6, r = b & 63;
                 transpose_tile(rdW + (size_t)l * 65536, rdt + (size_t)l * 65536,
                                1024, 64, r % 2, r / 2, tile); return; }
  b -= 128;
  if (b < 64)  { transpose_tile(ruW, rut, 64, 1024, b % 32, b / 32, tile); return; }
  b -= 64;
  if (b < 16384) { int l = b >> 10, r = b & 1023;
                 transpose_tile(eW + (size_t)l * 1048576, eWt + (size_t)l * 1048576,
                                1024, 1024, r % 32, r / 32, tile); return; }
  b -= 16384;
  if (b < 288) {  // Wh[o][e*1024+d] = aW[e][d][o] (o<8) | cW[e][d]
    int i = b * 256 + tid;
    int o = i / 8192, k = i - o * 8192;
    float v = (o < 8) ? aW[(size_t)k * 8 + o] : cW[k];
    Wh[i] = f2bf(v);
    return;
  }
  b -= 288;
  {  // split x(B,192) -> obs (B,128), task (B,64)
    int i = b * 256 + tid;
    int bb = i / 192, c = i - bb * 192;
    us v = f2bf(x[i]);
    if (c < 128) obs[(size_t)bb * 128 + c] = v;
    else         task[(size_t)bb * 64 + (c - 128)] = v;
  }
}

// pbf[i] = bf16(sum_{p<4} pbuf[p*n + i] + rdb[i&63])   (u-GEMM input)
__global__ __launch_bounds__(256)
void mk_pbf(const float* __restrict__ pbuf, const float* __restrict__ rdb,
            us* __restrict__ pbf, int n)
{
  int i = blockIdx.x * 256 + threadIdx.x;
  if (i >= n) return;
  const size_t pe = (size_t)n;
  float v = pbuf[i] + pbuf[pe + i] + pbuf[2 * pe + i] + pbuf[3 * pe + i]
          + rdb[i & 63];
  pbf[i] = f2bf(v);
}

// softmax over groups of 8.  Logits = sum of 4 split-K planes; layer0 groups
// (i < biasFrom) use planes 0..3 + bias2[0..63], layer1 planes 4..7 +
// bias2[64..127].  pe = plane elems (B*64).
__global__ __launch_bounds__(256)
void softmax8_kernel(const float* __restrict__ p, float* __restrict__ probs,
                     const float* __restrict__ bias2, int biasFrom, int total,
                     long long pe)
{
  int i = blockIdx.x * 256 + threadIdx.x;
  if (i >= total) return;
  const int layer = (i >= biasFrom) ? 1 : 0;
  const size_t li = (size_t)(layer ? i - biasFrom : i) * 8;
  const float* b0 = p + (size_t)(layer ? 4 : 0) * pe + li;
  const float* bb = bias2 + layer * 64 + (i & 7) * 8;
  float v[8];
#pragma unroll
  for (int j = 0; j < 8; ++j)
    v[j] = b0[j] + b0[pe + j] + b0[2 * pe + j] + b0[3 * pe + j] + bb[j];
  float m = v[0];
#pragma unroll
  for (int j = 1; j < 8; ++j) m = fmaxf(m, v[j]);
  float s = 0.f;
#pragma unroll
  for (int j = 0; j < 8; ++j) { v[j] = __expf(v[j] - m); s += v[j]; }
  float inv = 1.f / s;
  float4 olo = { v[0]*inv, v[1]*inv, v[2]*inv, v[3]*inv };
  float4 ohi = { v[4]*inv, v[5]*inv, v[6]*inv, v[7]*inv };
  *(float4*)(probs + (size_t)i * 8)     = olo;
  *(float4*)(probs + (size_t)i * 8 + 4) = ohi;
}

// xx[i][bl][d] = sum_j P[bg,i,j]*he[j][bl][d].  2 rows per block, 16B loads.
__global__ __launch_bounds__(256)
void mix_kernel(const us* __restrict__ he, const float* __restrict__ probs_l,
                us* __restrict__ xx, int b0, int chunkB,
                long long sOutE, long long sOutB)
{
  const int half = threadIdx.x >> 7;
  const int t = threadIdx.x & 127;
  const int bl = blockIdx.x * 2 + half;
  __shared__ float P[2][64];
  if (threadIdx.x < 128)
    P[threadIdx.x >> 6][threadIdx.x & 63] =
        probs_l[(size_t)(b0 + blockIdx.x * 2 + (threadIdx.x >> 6)) * 64 +
                (threadIdx.x & 63)];
  __syncthreads();
  const size_t es = (size_t)chunkB * 1024;
  const size_t rbase = (size_t)bl * 1024 + (size_t)t * 8;
  const size_t wbase = (size_t)bl * sOutB + (size_t)t * 8;
  float hv[8][8];
#pragma unroll
  for (int j = 0; j < 8; ++j) {
    short8 h8 = *(const short8*)(he + (size_t)j * es + rbase);
#pragma unroll
    for (int q = 0; q < 8; ++q) hv[j][q] = bf2f((us)h8[q]);
  }
  const float* Pr = P[half];
#pragma unroll
  for (int i = 0; i < 8; ++i) {
    float o[8];
#pragma unroll
    for (int q = 0; q < 8; ++q) o[q] = 0.f;
#pragma unroll
    for (int j = 0; j < 8; ++j) {
      float pij = Pr[i * 8 + j];
#pragma unroll
      for (int q = 0; q < 8; ++q) o[q] += pij * hv[j][q];
    }
    short8 ov;
#pragma unroll
    for (int q = 0; q < 8; ++q) ov[q] = (short)f2bf(o[q]);
    *(short8*)(xx + (size_t)i * sOutE + wbase) = ov;
  }
}

// ---------------------------------------------------------------------------
// mix_head: fused second mix + policy/value heads.  2 batch rows per block.
// out: mu = out[bg*8+o] (o<8), values = out[Btot*8+bg].
// ---------------------------------------------------------------------------
__global__ __launch_bounds__(256)
void mix_head_kernel(const us* __restrict__ he, const float* __restrict__ probs_l,
                     const us* __restrict__ Wh, const float* __restrict__ ab,
                     const float* __restrict__ cb, float* __restrict__ out,
                     int b0, int chunkB, int Btot)
{
  const int r0 = blockIdx.x * 2;            // local row pair
  const int t = threadIdx.x;
  const int lane = t & 63;
  const int wave = t >> 6;
  __shared__ float P[2][64];
  __shared__ float red[2][9][4];
  if (t < 128)
    P[t >> 6][t & 63] = probs_l[(size_t)(b0 + r0 + (t >> 6)) * 64 + (t & 63)];
  __syncthreads();

  const size_t es = (size_t)chunkB * 1024;
  float xv[2][8][4];
#pragma unroll
  for (int r = 0; r < 2; ++r) {
#pragma unroll
    for (int i = 0; i < 8; ++i)
#pragma unroll
      for (int q = 0; q < 4; ++q) xv[r][i][q] = 0.f;
    const size_t rbase = (size_t)(r0 + r) * 1024 + (size_t)t * 4;
#pragma unroll
    for (int j = 0; j < 8; ++j) {
      ushort4 h4 = *(const ushort4*)(he + (size_t)j * es + rbase);
      float h0 = bf2f(h4.x), h1 = bf2f(h4.y), h2 = bf2f(h4.z), h3 = bf2f(h4.w);
#pragma unroll
      for (int i = 0; i < 8; ++i) {
        float p = P[r][i * 8 + j];
        xv[r][i][0] += p * h0; xv[r][i][1] += p * h1;
        xv[r][i][2] += p * h2; xv[r][i][3] += p * h3;
      }
    }
  }

  // head: s[r][o] = sum_{i,q} xv[r][i][q] * Wh[o][i*1024 + t*4 + q]
  float s[2][9];
#pragma unroll
  for (int o = 0; o < 9; ++o) { s[0][o] = 0.f; s[1][o] = 0.f; }
#pragma unroll
  for (int o = 0; o < 9; ++o) {
    const us* w = Wh + (size_t)o * 8192 + (size_t)t * 4;
#pragma unroll
    for (int i = 0; i < 8; ++i) {
      ushort4 w4 = *(const ushort4*)(w + i * 1024);
      float w0 = bf2f(w4.x), w1 = bf2f(w4.y), w2 = bf2f(w4.z), w3 = bf2f(w4.w);
      s[0][o] += xv[0][i][0]*w0 + xv[0][i][1]*w1 + xv[0][i][2]*w2 + xv[0][i][3]*w3;
      s[1][o] += xv[1][i][0]*w0 + xv[1][i][1]*w1 + xv[1][i][2]*w2 + xv[1][i][3]*w3;
    }
  }

  // wave shuffle-reduce (64-wide), then cross-wave via LDS
#pragma unroll
  for (int off = 32; off >= 1; off >>= 1) {
#pragma unroll
    for (int r = 0; r < 2; ++r)
#pragma unroll
      for (int o = 0; o < 9; ++o) s[r][o] += __shfl_down(s[r][o], off);
  }
  if (lane == 0) {
#pragma unroll
    for (int r = 0; r < 2; ++r)
#pragma unroll
      for (int o = 0; o < 9; ++o) red[r][o][wave] = s[r][o];
  }
  __syncthreads();
  if (t < 18) {
    int r = t / 9, o = t - r * 9;
    float v = red[r][o][0] + red[r][o][1] + red[r][o][2] + red[r][o][3];
    float bias = 0.f;
    if (o < 8) { for (int e = 0; e < 8; ++e) bias += ab[e * 8 + o]; }
    else       { for (int e = 0; e < 8; ++e) bias += cb[e]; }
    int bg = b0 + r0 + r;
    if (o < 8) out[(size_t)bg * 8 + o] = v + bias;
    else       out[(size_t)Btot * 8 + bg] = v + bias;
  }
}

// ---------------------------------------------------------------------------
extern "C" void kernel_launch(void* const* d_in, const int* in_sizes, int n_in,
                              void* d_out, int out_size, void* d_ws, size_t ws_size,
                              hipStream_t stream)
{
  const float* x   = (const float*)d_in[0];
  const float* sW1 = (const float*)d_in[1];
  const float* sb1 = (const float*)d_in[2];
  const float* sW2 = (const float*)d_in[3];
  const float* sb2 = (const float*)d_in[4];
  const float* sW3 = (const float*)d_in[5];
  const float* sb3 = (const float*)d_in[6];
  const float* tW  = (const float*)d_in[7];
  const float* tb  = (const float*)d_in[8];
  const float* rdW = (const float*)d_in[9];
  const float* rdb = (const float*)d_in[10];
  const float* ruW = (const float*)d_in[11];
  const float* rub = (const float*)d_in[12];
  const float* eW  = (const float*)d_in[13];
  const float* eb  = (const float*)d_in[14];
  const float* aW  = (const float*)d_in[15];
  const float* ab  = (const float*)d_in[16];
  const float* cW  = (const float*)d_in[17];
  const float* cb  = (const float*)d_in[18];
  float* out = (float*)d_out;

  const int B = 8192;
  const size_t BD = (size_t)B * 1024;
  char* ws = (char*)d_ws;

  // ---- arena: persistent region -------------------------------------------
  size_t o = 0;
  auto take = [&](size_t bytes) { size_t r = o; o = (o + bytes + 255) & ~(size_t)255; return r; };
  const size_t off_s1t  = take((size_t)512 * 128 * 2);
  const size_t off_s2t  = take((size_t)512 * 512 * 2);
  const size_t off_s3t  = take((size_t)1024 * 512 * 2);
  const size_t off_tWt  = take((size_t)1024 * 64 * 2);
  const size_t off_rdt  = take((size_t)2 * 64 * 1024 * 2);
  const size_t off_rut  = take((size_t)1024 * 64 * 2);
  const size_t off_eWt  = take((size_t)16 * 1024 * 1024 * 2);
  const size_t off_fobs = take(BD * 2);
  const size_t off_probs= take((size_t)2 * B * 64 * 4);
  const size_t off_Wh   = take((size_t)9 * 8192 * 2);
  const size_t P0 = o;
  // ---- scratch overlays (routing phase) -----------------------------------
  const size_t off_rin  = P0;                 // also h1
  const size_t off_rbuf = off_rin + BD * 2;   // also h2, u
  const size_t off_pbuf = off_rbuf + BD * 2;  // 8 split-K planes (4/layer)
  const size_t off_pbf  = off_pbuf + (size_t)8 * B * 64 * 4;
  const size_t off_obs  = off_pbf + (size_t)B * 64 * 2;
  const size_t off_task = off_obs + (size_t)B * 128 * 2;
  const size_t routing_end = off_task + (size_t)B * 64 * 2;

  // ---- expert-stage chunk selection (he/xx overlay scratch at P0) ---------
  // Prefer 2048: he+xx (66MB) + eWt (32MB) stay Infinity-Cache-resident.
  int chunk = 0;
  const int cands[4] = {2048, 1024, 512, 256};
  for (int i = 0; i < 4; ++i) {
    size_t need = P0 + (size_t)cands[i] * 32768;  // he + xx
    if (need <= ws_size) { chunk = cands[i]; break; }
  }
  if (!chunk || routing_end > ws_size) return;

  us* s1t  = (us*)(ws + off_s1t);
  us* s2t  = (us*)(ws + off_s2t);
  us* s3t  = (us*)(ws + off_s3t);
  us* tWt  = (us*)(ws + off_tWt);
  us* rdt  = (us*)(ws + off_rdt);
  us* rut  = (us*)(ws + off_rut);
  us* eWt  = (us*)(ws + off_eWt);
  us* fobs = (us*)(ws + off_fobs);
  float* probs = (float*)(ws + off_probs);
  us* Wh   = (us*)(ws + off_Wh);
  us* rin  = (us*)(ws + off_rin);
  us* rbuf = (us*)(ws + off_rbuf);
  float* pbuf = (float*)(ws + off_pbuf);
  us* pbf  = (us*)(ws + off_pbf);
  us* obs_bf  = (us*)(ws + off_obs);
  us* task_bf = (us*)(ws + off_task);
  us* h1 = rin;
  us* h2 = rbuf;
  us* he = (us*)(ws + P0);
  us* xx = (us*)(ws + P0 + (size_t)chunk * 16384);

  // ---- fused prep: transposes + Wh + x split ------------------------------
  prep_kernel<<<dim3(23904), 256, 0, stream>>>(x, sW1, sW2, sW3, tW, rdW, ruW,
      eW, aW, cW, obs_bf, task_bf, s1t, s2t, s3t, tWt, rdt, rut, eWt, Wh);

  // ---- shared MLP ---------------------------------------------------------
  gemm_main<true, true, false, false, false><<<dim3(4, 64, 1), 256, 0, stream>>>(
      obs_bf, s1t, sb1, h1, (us*)0, (const us*)0, 512, 128, 128, 128, 0, 0, 0, 0);
  gemm_main<true, true, false, false, false><<<dim3(4, 64, 1), 256, 0, stream>>>(
      h1, s2t, sb2, h2, (us*)0, (const us*)0, 512, 512, 512, 512, 0, 0, 0, 0);
  gemm_main<true, false, false, false, false><<<dim3(8, 64, 1), 256, 0, stream>>>(
      h2, s3t, sb3, fobs, (us*)0, (const us*)0, 1024, 512, 512, 512, 0, 0, 0, 0);
  // z-GEMM fused: rin = relu(task@tW+tb)*fobs ; rbuf = relu(rin)
  gemm_main<true, true, true, false, true><<<dim3(8, 64, 1), 256, 0, stream>>>(
      task_bf, tWt, tb, rin, rbuf, fobs, 1024, 64, 64, 64, 0, 0, 0, 0);

  // ---- routing (layers 0,1; layer 2 is dead code) -------------------------
  gemm_splitk<<<dim3(1, 64, 4), 256, 0, stream>>>(rbuf, rdt, pbuf,
      64, 256, 1024, 1024, 256, 256);                                // p0
  mk_pbf<<<dim3((B * 64 + 255) / 256), 256, 0, stream>>>(pbuf, rdb, pbf, B * 64);
  // u-GEMM fused: rbuf = relu((pbf@ruW+rub) * rin)
  gemm_main<true, false, true, true, false><<<dim3(8, 64, 1), 256, 0, stream>>>(
      pbf, rut, rub, rbuf, (us*)0, rin, 1024, 64, 64, 64, 0, 0, 0, 0);
  gemm_splitk<<<dim3(1, 64, 4), 256, 0, stream>>>(rbuf, rdt + 65536,
      pbuf + (size_t)4 * B * 64, 64, 256, 1024, 1024, 256, 256);     // p1
  softmax8_kernel<<<dim3((2 * B * 8 + 255) / 256), 256, 0, stream>>>(
      pbuf, probs, rdb, B * 8, 2 * B * 8, (long long)B * 64);

  // ---- expert stage, chunked over batch (L3-resident at chunk=2048) -------
  const long long sHE = (long long)chunk * 1024;
  for (int b0 = 0; b0 < B; b0 += chunk) {
    gemm_n256<true, true><<<dim3(4, chunk / 256, 8), 512, 0, stream>>>(
        fobs + (size_t)b0 * 1024, eWt, eb, he,
        1024, 1024, 1024, 1024, 0, 1048576, 1024, sHE);
    mix_kernel<<<dim3(chunk / 2), 256, 0, stream>>>(he, probs, xx, b0, chunk, sHE, 1024);
    gemm_n256<true, true><<<dim3(4, chunk / 256, 8), 512, 0, stream>>>(
        xx, eWt + (size_t)8 * 1048576, eb + 8192, he,
        1024, 1024, 1024, 1024, sHE, 1048576, 1024, sHE);
    // fused second mix + heads: no xx b-major materialization, no atomics
    mix_head_kernel<<<dim3(chunk / 2), 256, 0, stream>>>(
        he, probs + (size_t)B * 64, Wh, ab, cb, out, b0, chunk, B);
  }
}

// Round 8
// 683.975 us; speedup vs baseline: 1.0277x; 1.0277x over previous
//
#include <hip/hip_runtime.h>

// ---------------------------------------------------------------------------
// SharedPPOSoftModularizedMLP on MI355X (gfx950)
// B=8192, OBS=128, TASK=64, D=1024, E=8, L=4
// bf16 MFMA (16x16x32), fp32 accumulate.
// R16: chunk 2048 -> 4096.  R15 showed chunk=2048 L3-residency was nulled by
//      +12 launch gaps (~35us) exactly offsetting the L3 gain (~35-40us).
//      At 4096 the working set (he+xx 134MB + eWt 32MB = 166MB) is still
//      Infinity-Cache-resident but only +4 launches vs the 8192 config.
//      Everything else identical to R15 (which passed, 703us).
// ---------------------------------------------------------------------------

typedef __attribute__((ext_vector_type(8))) short short8;   // 8 x bf16 frag
typedef __attribute__((ext_vector_type(4))) float floatx4;  // MFMA acc
typedef unsigned short us;

__device__ __forceinline__ us f2bf(float f) {
  union { float f; unsigned u; } v; v.f = f;
  return (us)((v.u + 0x7FFFu + ((v.u >> 16) & 1u)) >> 16);  // RNE
}
__device__ __forceinline__ float bf2f(us h) {
  union { unsigned u; float f; } v; v.u = ((unsigned)h) << 16;
  return v.f;
}

// async global->LDS, 16B per lane; lds dest = wave-uniform base + lane*16
__device__ __forceinline__ void g2lds16(const void* g, void* l) {
  __builtin_amdgcn_global_load_lds(
      (const __attribute__((address_space(1))) void*)g,
      (__attribute__((address_space(3))) void*)l, 16, 0, 0);
}

// ---------------------------------------------------------------------------
// Main-path GEMM: C[M,N] = post(act(A@Bt^T + bias)); all bf16, M,N %128==0.
// post: MUL -> elementwise * Mul[M,N]; RELU2 -> relu after MUL.
// CB2: Cb = value, Cb2 = relu(value).
// grid=(N/128, M/128, E). XCD chunk swizzle when total blocks % 8 == 0.
// ---------------------------------------------------------------------------
template<bool BIAS, bool RELU, bool MUL, bool RELU2, bool CB2>
__global__ __launch_bounds__(256)
void gemm_main(const us* __restrict__ A, const us* __restrict__ Bt,
               const float* __restrict__ bias,
               us* __restrict__ Cb, us* __restrict__ Cb2,
               const us* __restrict__ Mul,
               int N, int K, int lda, int ldb,
               long long sA, long long sB, long long sBias, long long sC)
{
  // ---- XCD chunk swizzle ----
  int bx = blockIdx.x, by = blockIdx.y, bz = blockIdx.z;
  {
    const int gx = gridDim.x, gy = gridDim.y;
    const int total = gx * gy * gridDim.z;
    if ((total & 7) == 0) {
      int L = bx + gx * (by + gy * bz);
      int per = total >> 3;
      int w = (L & 7) * per + (L >> 3);
      bx = w % gx; w /= gx;
      by = w % gy; bz = w / gy;
    }
  }

  const int e = bz;
  const us* Ab = A + (size_t)e * sA;
  const us* Bb = Bt + (size_t)e * sB;

  const int m0 = by * 128;
  const int n0 = bx * 128;
  const int tid = threadIdx.x;
  const int wave = tid >> 6;
  const int lane = tid & 63;
  const int wm = (wave >> 1) * 64;
  const int wn = (wave & 1) * 64;
  const int lr = lane & 15;
  const int lq = lane >> 4;

  // staging: A = smem[0..8191], B = smem[8192..16383]  (us units)
  // epilogue tile: smem[0..17407] as [128][136] us  (R4 layout)
  __shared__ __align__(16) us smem[128 * 136 + 64];
  us* ldsA = smem;
  us* ldsB = smem + 128 * 64;

  floatx4 acc[4][4];
#pragma unroll
  for (int i = 0; i < 4; ++i)
#pragma unroll
    for (int j = 0; j < 4; ++j) acc[i][j] = (floatx4){0.f, 0.f, 0.f, 0.f};

  for (int k0 = 0; k0 < K; k0 += 64) {
#pragma unroll
    for (int c = 0; c < 4; ++c) {
      int slot = c * 256 + tid;               // physical 16B chunk
      int r = slot >> 3;
      int s = (slot & 7) ^ (r & 7);           // logical slab (XOR swizzle)
      int ubase = (c * 256 + wave * 64) * 8;  // wave-uniform LDS base (us)
      g2lds16(Ab + (size_t)(m0 + r) * lda + k0 + s * 8, ldsA + ubase);
      g2lds16(Bb + (size_t)(n0 + r) * ldb + k0 + s * 8, ldsB + ubase);
    }
    __syncthreads();

#pragma unroll
    for (int kk = 0; kk < 2; ++kk) {
      short8 af[4], bfr[4];
#pragma unroll
      for (int t = 0; t < 4; ++t) {
        int m = wm + t * 16 + lr;
        int s = kk * 4 + lq;
        af[t]  = *(const short8*)(ldsA + (size_t)(m * 8 + (s ^ (m & 7))) * 8);
        int n = wn + t * 16 + lr;
        bfr[t] = *(const short8*)(ldsB + (size_t)(n * 8 + (s ^ (n & 7))) * 8);
      }
#pragma unroll
      for (int mt = 0; mt < 4; ++mt)
#pragma unroll
        for (int nt = 0; nt < 4; ++nt)
          acc[mt][nt] = __builtin_amdgcn_mfma_f32_16x16x32_bf16(
              af[mt], bfr[nt], acc[mt][nt], 0, 0, 0);
    }
    __syncthreads();
  }

  // ---- epilogue (R4): stage bf16 tile in LDS [128][136], store dwordx4 ----
  // C/D layout: col = lane&15, row = lq*4 + r
#pragma unroll
  for (int nt = 0; nt < 4; ++nt) {
    int coll = wn + nt * 16 + lr;
    int col = n0 + coll;
    float bv = BIAS ? bias[(size_t)e * sBias + col] : 0.f;
#pragma unroll
    for (int mt = 0; mt < 4; ++mt) {
      int rowb = wm + mt * 16 + lq * 4;
#pragma unroll
      for (int r = 0; r < 4; ++r) {
        int rowl = rowb + r;
        float v = acc[mt][nt][r] + bv;
        if (RELU) v = fmaxf(v, 0.f);
        if (MUL) v *= bf2f(Mul[(size_t)(m0 + rowl) * N + col]);
        if (RELU2) v = fmaxf(v, 0.f);
        smem[rowl * 136 + coll] = f2bf(v);
      }
    }
  }
  __syncthreads();
#pragma unroll
  for (int c = 0; c < 8; ++c) {
    int sl = c * 256 + tid;
    int rowl = sl >> 4;
    int seg = sl & 15;
    short8 val = *(const short8*)(smem + rowl * 136 + seg * 8);
    size_t gidx = (size_t)e * sC + (size_t)(m0 + rowl) * N + n0 + seg * 8;
    *(short8*)(Cb + gidx) = val;
    if (CB2) {
      short8 rl;
#pragma unroll
      for (int q = 0; q < 8; ++q) {
        us u = (us)val[q];
        rl[q] = (short)((u & 0x8000u) ? (us)0 : u);
      }
      *(short8*)(Cb2 + gidx) = rl;
    }
  }
}

// ---------------------------------------------------------------------------
// gemm_n256: deep-pipelined 256x256-tile GEMM (R10/R13 verified: MfmaUtil 36,
// 0 bank conflicts; 851 TF = m248 grouped mark for this shape).
//   C[M,N] = relu?(A@Bt^T + bias), bf16 in/out, fp32 acc.
//   Requirements: M%256==0, N%256==0, K%32==0, K>=128.
//   grid = (N/256, M/256, E), block = 512 (8 waves, 2M x 4N).
// ---------------------------------------------------------------------------
template<bool BIAS, bool RELU>
__global__ __launch_bounds__(512, 2)
void gemm_n256(const us* __restrict__ A, const us* __restrict__ Bt,
               const float* __restrict__ bias, us* __restrict__ Cb,
               int N, int K, int lda, int ldb,
               long long sA, long long sB, long long sBias, long long sC)
{
  // ---- XCD chunk swizzle (grid here is always %8==0) ----
  int bx = blockIdx.x, by = blockIdx.y, bz = blockIdx.z;
  {
    const int gx = gridDim.x, gy = gridDim.y;
    const int total = gx * gy * gridDim.z;
    if ((total & 7) == 0) {
      int L = bx + gx * (by + gy * bz);
      int per = total >> 3;
      int w = (L & 7) * per + (L >> 3);
      bx = w % gx; w /= gx;
      by = w % gy; bz = w / gy;
    }
  }
  const int e = bz;
  const us* Ab = A + (size_t)e * sA;
  const us* Bb = Bt + (size_t)e * sB;

  const int m0 = by * 256;
  const int n0 = bx * 256;
  const int tid  = threadIdx.x;
  const int wave = tid >> 6;
  const int lane = tid & 63;
  const int wm = (wave >> 2) * 128;   // 2 M-waves x 128 rows
  const int wn = (wave & 3) * 64;     // 4 N-waves x 64 cols
  const int lr = lane & 15;
  const int lq = lane >> 4;

  // LDS ring: A subs at [0 .. 32767], B subs at [32768 .. 65535] (us units).
  // Each sub = 256 rows x 32 K bf16 = 8192 us.  Within a sub, element
  // (row, slab) [slab = 8-bf16 16B unit, 0..3] lives in 128B line
  // L = row>>1 at position p = (slab | ((row&1)<<2)) ^ (L&7).
  __shared__ __align__(16) us smem[65536];

  floatx4 acc[8][4];
#pragma unroll
  for (int i = 0; i < 8; ++i)
#pragma unroll
    for (int j = 0; j < 4; ++j) acc[i][j] = (floatx4){0.f, 0.f, 0.f, 0.f};

  // ---- per-thread staging constants (2 A-loads + 2 B-loads per sub) ----
  const us* srcA[2];
  const us* srcB[2];
#pragma unroll
  for (int i = 0; i < 2; ++i) {
    int c   = i * 512 + tid;        // physical 16B chunk 0..1023
    int Ln  = c >> 3;               // 128B line
    int pos = c & 7;
    int q   = pos ^ (Ln & 7);
    int row = 2 * Ln + (q >> 2);    // logical row 0..255
    int so  = (q & 3) * 8;          // logical slab offset (us)
    srcA[i] = Ab + (size_t)(m0 + row) * lda + so;
    srcB[i] = Bb + (size_t)(n0 + row) * ldb + so;
  }
  const int dst0 = wave * 512;      // wave-uniform LDS chunk base (us)

  // ---- per-lane fragment read offsets (constant across phases) ----
  int offA[8], offB[4];
#pragma unroll
  for (int t = 0; t < 8; ++t) {
    int m  = wm + t * 16 + lr;
    int Ln = m >> 1;
    offA[t] = Ln * 64 + (((lq | ((m & 1) << 2)) ^ (Ln & 7)) << 3);
  }
#pragma unroll
  for (int t = 0; t < 4; ++t) {
    int n  = wn + t * 16 + lr;
    int Ln = n >> 1;
    offB[t] = Ln * 64 + (((lq | ((n & 1) << 2)) ^ (Ln & 7)) << 3);
  }

  auto stage = [&](int s) {
    us* a = smem + (s & 3) * 8192;
    us* b = smem + 32768 + (s & 3) * 8192;
    const int ko = s << 5;          // global k offset (elements)
#pragma unroll
    for (int i = 0; i < 2; ++i) g2lds16(srcA[i] + ko, a + dst0 + i * 4096);
#pragma unroll
    for (int i = 0; i < 2; ++i) g2lds16(srcB[i] + ko, b + dst0 + i * 4096);
  };

  auto compute = [&](int bufi) {
    const us* a = smem + bufi * 8192;
    const us* b = smem + 32768 + bufi * 8192;
    short8 af[8], bfr[4];
#pragma unroll
    for (int t = 0; t < 4; ++t) bfr[t] = *(const short8*)(b + offB[t]);
#pragma unroll
    for (int t = 0; t < 8; ++t) af[t] = *(const short8*)(a + offA[t]);
    __builtin_amdgcn_s_setprio(1);
#pragma unroll
    for (int mt = 0; mt < 8; ++mt)
#pragma unroll
      for (int nt = 0; nt < 4; ++nt)
        acc[mt][nt] = __builtin_amdgcn_mfma_f32_16x16x32_bf16(
            af[mt], bfr[nt], acc[mt][nt], 0, 0, 0);
    __builtin_amdgcn_s_setprio(0);
  };

  // ---- prologue: 3 sub-tiles in flight ----
  stage(0); stage(1); stage(2);

  const int NP = K >> 5;            // phases (>=4 by contract)
  for (int p = 0; p < NP - 3; ++p) {
    asm volatile("s_waitcnt vmcnt(8)" ::: "memory");
    __builtin_amdgcn_s_barrier();
    __builtin_amdgcn_sched_barrier(0);
    stage(p + 3);
    compute(p & 3);
  }
  // ---- tail: drain 8 -> 4 -> 0 ----
  asm volatile("s_waitcnt vmcnt(8)" ::: "memory");
  __builtin_amdgcn_s_barrier();
  __builtin_amdgcn_sched_barrier(0);
  compute((NP - 3) & 3);
  asm volatile("s_waitcnt vmcnt(4)" ::: "memory");
  __builtin_amdgcn_s_barrier();
  __builtin_amdgcn_sched_barrier(0);
  compute((NP - 2) & 3);
  asm volatile("s_waitcnt vmcnt(0)" ::: "memory");
  __builtin_amdgcn_s_barrier();
  __builtin_amdgcn_sched_barrier(0);
  compute((NP - 1) & 3);

  // ---- epilogue: bias+relu, bf16 via swizzled LDS [256][256], 16B stores --
  __syncthreads();
#pragma unroll
  for (int nt = 0; nt < 4; ++nt) {
    int coll = wn + nt * 16 + lr;
    float bv = BIAS ? bias[(size_t)e * sBias + n0 + coll] : 0.f;
#pragma unroll
    for (int mt = 0; mt < 8; ++mt) {
      int rowb = wm + mt * 16 + lq * 4;
#pragma unroll
      for (int r = 0; r < 4; ++r) {
        int row = rowb + r;
        float v = acc[mt][nt][r] + bv;
        if (RELU) v = fmaxf(v, 0.f);
        smem[row * 256 + (coll ^ (((row >> 2) & 3) << 4))] = f2bf(v);
      }
    }
  }
  __syncthreads();
#pragma unroll
  for (int c = 0; c < 16; ++c) {
    int sl  = c * 512 + tid;
    int row = sl >> 5;
    int ch  = sl & 31;
    short8 val = *(const short8*)(smem + row * 256 +
                                  ((ch * 8) ^ (((row >> 2) & 3) << 4)));
    *(short8*)(Cb + (size_t)e * sC + (size_t)(m0 + row) * N + n0 + ch * 8) = val;
  }
}

// ---------------------------------------------------------------------------
// Split-K GEMM, non-atomic: k-chunk bz writes its fp32 partial to plane bz of
// Cf (plane = M*N floats, M = gridDim.y*128).  Consumers sum the planes.
// N may be < 128 (B-row clamp).  Used for routing p0/p1 (N=64, 4 k-chunks).
// ---------------------------------------------------------------------------
__global__ __launch_bounds__(256)
void gemm_splitk(const us* __restrict__ A, const us* __restrict__ Bt,
                 float* __restrict__ Cf,
                 int N, int K, int lda, int ldb,
                 long long sA, long long sB)
{
  int bx = blockIdx.x, by = blockIdx.y, bz = blockIdx.z;
  {
    const int gx = gridDim.x, gy = gridDim.y;
    const int total = gx * gy * gridDim.z;
    if ((total & 7) == 0) {
      int L = bx + gx * (by + gy * bz);
      int per = total >> 3;
      int w = (L & 7) * per + (L >> 3);
      bx = w % gx; w /= gx;
      by = w % gy; bz = w / gy;
    }
  }

  const us* Ab = A + (size_t)bz * sA;
  const us* Bb = Bt + (size_t)bz * sB;
  float* Cp = Cf + (size_t)bz * (size_t)gridDim.y * 128 * N;  // plane bz

  const int m0 = by * 128;
  const int n0 = bx * 128;
  const int tid = threadIdx.x;
  const int wave = tid >> 6;
  const int lane = tid & 63;
  const int wm = (wave >> 1) * 64;
  const int wn = (wave & 1) * 64;
  const int lr = lane & 15;
  const int lq = lane >> 4;

  __shared__ __align__(16) us smem[128 * 128];
  us* ldsA = smem;
  us* ldsB = smem + 128 * 64;

  floatx4 acc[4][4];
#pragma unroll
  for (int i = 0; i < 4; ++i)
#pragma unroll
    for (int j = 0; j < 4; ++j) acc[i][j] = (floatx4){0.f, 0.f, 0.f, 0.f};

  for (int k0 = 0; k0 < K; k0 += 64) {
#pragma unroll
    for (int c = 0; c < 4; ++c) {
      int slot = c * 256 + tid;
      int r = slot >> 3;
      int s = (slot & 7) ^ (r & 7);
      int ubase = (c * 256 + wave * 64) * 8;
      g2lds16(Ab + (size_t)(m0 + r) * lda + k0 + s * 8, ldsA + ubase);
      int nrow = n0 + r; if (nrow > N - 1) nrow = N - 1;  // clamp (N<128)
      g2lds16(Bb + (size_t)nrow * ldb + k0 + s * 8, ldsB + ubase);
    }
    __syncthreads();

#pragma unroll
    for (int kk = 0; kk < 2; ++kk) {
      short8 af[4], bfr[4];
#pragma unroll
      for (int t = 0; t < 4; ++t) {
        int m = wm + t * 16 + lr;
        int s = kk * 4 + lq;
        af[t]  = *(const short8*)(ldsA + (size_t)(m * 8 + (s ^ (m & 7))) * 8);
        int n = wn + t * 16 + lr;
        bfr[t] = *(const short8*)(ldsB + (size_t)(n * 8 + (s ^ (n & 7))) * 8);
      }
#pragma unroll
      for (int mt = 0; mt < 4; ++mt)
#pragma unroll
        for (int nt = 0; nt < 4; ++nt)
          acc[mt][nt] = __builtin_amdgcn_mfma_f32_16x16x32_bf16(
              af[mt], bfr[nt], acc[mt][nt], 0, 0, 0);
    }
    __syncthreads();
  }

#pragma unroll
  for (int nt = 0; nt < 4; ++nt) {
    int col = n0 + wn + nt * 16 + lr;
    if (col >= N) continue;
#pragma unroll
    for (int mt = 0; mt < 4; ++mt) {
      int row = m0 + wm + mt * 16 + lq * 4;
#pragma unroll
      for (int r = 0; r < 4; ++r)
        Cp[(size_t)(row + r) * N + col] = acc[mt][nt][r];
    }
  }
}

// ---------------------------------------------------------------------------
// Fused prep: all weight transposes (fp32 [R,C] -> bf16 [C,R]), Wh build,
// x split/convert.  One launch, range ladder.
// ---------------------------------------------------------------------------
__device__ __forceinline__ void transpose_tile(
    const float* __restrict__ in, us* __restrict__ out,
    int R, int C, int bx, int by, float (*tile)[33])
{
  const int tx = threadIdx.x & 31, ty = threadIdx.x >> 5;
  const int c0 = bx * 32, r0 = by * 32;
#pragma unroll
  for (int i = 0; i < 4; ++i) {
    int r = r0 + ty + i * 8, c = c0 + tx;
    tile[ty + i * 8][tx] = (r < R && c < C) ? in[(size_t)r * C + c] : 0.f;
  }
  __syncthreads();
#pragma unroll
  for (int i = 0; i < 4; ++i) {
    int c = c0 + ty + i * 8, r = r0 + tx;
    if (c < C && r < R) out[(size_t)c * R + r] = f2bf(tile[tx][ty + i * 8]);
  }
}

__global__ __launch_bounds__(256)
void prep_kernel(const float* __restrict__ x,
                 const float* __restrict__ sW1, const float* __restrict__ sW2,
                 const float* __restrict__ sW3, const float* __restrict__ tW,
                 const float* __restrict__ rdW, const float* __restrict__ ruW,
                 const float* __restrict__ eW,
                 const float* __restrict__ aW, const float* __restrict__ cW,
                 us* __restrict__ obs, us* __restrict__ task,
                 us* __restrict__ s1t, us* __restrict__ s2t,
                 us* __restrict__ s3t, us* __restrict__ tWt,
                 us* __restrict__ rdt, us* __restrict__ rut,
                 us* __restrict__ eWt, us* __restrict__ Wh)
{
  __shared__ float tile[32][33];
  int b = blockIdx.x;
  const int tid = threadIdx.x;

  if (b < 64)  { transpose_tile(sW1, s1t, 128, 512, b % 16, b / 16, tile); return; }
  b -= 64;
  if (b < 256) { transpose_tile(sW2, s2t, 512, 512, b % 16, b / 16, tile); return; }
  b -= 256;
  if (b < 512) { transpose_tile(sW3, s3t, 512, 1024, b % 32, b / 32, tile); return; }
  b -= 512;
  if (b < 64)  { transpose_tile(tW, tWt, 64, 1024, b % 32, b / 32, tile); return; }
  b -= 64;
  if (b < 128) { int l = b >> 6, r = b & 63;
                 transpose_tile(rdW + (size_t)l * 65536, rdt + (size_t)l * 65536,
                                1024, 64, r % 2, r / 2, tile); return; }
  b -= 128;
  if (b < 64)  { transpose_tile(ruW, rut, 64, 1024, b % 32, b / 32, tile); return; }
  b -= 64;
  if (b < 16384) { int l = b >> 10, r = b & 1023;
                 transpose_tile(eW + (size_t)l * 1048576, eWt + (size_t)l * 1048576,
                                1024, 1024, r % 32, r / 32, tile); return; }
  b -= 16384;
  if (b < 288) {  // Wh[o][e*1024+d] = aW[e][d][o] (o<8) | cW[e][d]
    int i = b * 256 + tid;
    int o = i / 8192, k = i - o * 8192;
    float v = (o < 8) ? aW[(size_t)k * 8 + o] : cW[k];
    Wh[i] = f2bf(v);
    return;
  }
  b -= 288;
  {  // split x(B,192) -> obs (B,128), task (B,64)
    int i = b * 256 + tid;
    int bb = i / 192, c = i - bb * 192;
    us v = f2bf(x[i]);
    if (c < 128) obs[(size_t)bb * 128 + c] = v;
    else         task[(size_t)bb * 64 + (c - 128)] = v;
  }
}

// pbf[i] = bf16(sum_{p<4} pbuf[p*n + i] + rdb[i&63])   (u-GEMM input)
__global__ __launch_bounds__(256)
void mk_pbf(const float* __restrict__ pbuf, const float* __restrict__ rdb,
            us* __restrict__ pbf, int n)
{
  int i = blockIdx.x * 256 + threadIdx.x;
  if (i >= n) return;
  const size_t pe = (size_t)n;
  float v = pbuf[i] + pbuf[pe + i] + pbuf[2 * pe + i] + pbuf[3 * pe + i]
          + rdb[i & 63];
  pbf[i] = f2bf(v);
}

// softmax over groups of 8.  Logits = sum of 4 split-K planes; layer0 groups
// (i < biasFrom) use planes 0..3 + bias2[0..63], layer1 planes 4..7 +
// bias2[64..127].  pe = plane elems (B*64).
__global__ __launch_bounds__(256)
void softmax8_kernel(const float* __restrict__ p, float* __restrict__ probs,
                     const float* __restrict__ bias2, int biasFrom, int total,
                     long long pe)
{
  int i = blockIdx.x * 256 + threadIdx.x;
  if (i >= total) return;
  const int layer = (i >= biasFrom) ? 1 : 0;
  const size_t li = (size_t)(layer ? i - biasFrom : i) * 8;
  const float* b0 = p + (size_t)(layer ? 4 : 0) * pe + li;
  const float* bb = bias2 + layer * 64 + (i & 7) * 8;
  float v[8];
#pragma unroll
  for (int j = 0; j < 8; ++j)
    v[j] = b0[j] + b0[pe + j] + b0[2 * pe + j] + b0[3 * pe + j] + bb[j];
  float m = v[0];
#pragma unroll
  for (int j = 1; j < 8; ++j) m = fmaxf(m, v[j]);
  float s = 0.f;
#pragma unroll
  for (int j = 0; j < 8; ++j) { v[j] = __expf(v[j] - m); s += v[j]; }
  float inv = 1.f / s;
  float4 olo = { v[0]*inv, v[1]*inv, v[2]*inv, v[3]*inv };
  float4 ohi = { v[4]*inv, v[5]*inv, v[6]*inv, v[7]*inv };
  *(float4*)(probs + (size_t)i * 8)     = olo;
  *(float4*)(probs + (size_t)i * 8 + 4) = ohi;
}

// xx[i][bl][d] = sum_j P[bg,i,j]*he[j][bl][d].  2 rows per block, 16B loads.
__global__ __launch_bounds__(256)
void mix_kernel(const us* __restrict__ he, const float* __restrict__ probs_l,
                us* __restrict__ xx, int b0, int chunkB,
                long long sOutE, long long sOutB)
{
  const int half = threadIdx.x >> 7;
  const int t = threadIdx.x & 127;
  const int bl = blockIdx.x * 2 + half;
  __shared__ float P[2][64];
  if (threadIdx.x < 128)
    P[threadIdx.x >> 6][threadIdx.x & 63] =
        probs_l[(size_t)(b0 + blockIdx.x * 2 + (threadIdx.x >> 6)) * 64 +
                (threadIdx.x & 63)];
  __syncthreads();
  const size_t es = (size_t)chunkB * 1024;
  const size_t rbase = (size_t)bl * 1024 + (size_t)t * 8;
  const size_t wbase = (size_t)bl * sOutB + (size_t)t * 8;
  float hv[8][8];
#pragma unroll
  for (int j = 0; j < 8; ++j) {
    short8 h8 = *(const short8*)(he + (size_t)j * es + rbase);
#pragma unroll
    for (int q = 0; q < 8; ++q) hv[j][q] = bf2f((us)h8[q]);
  }
  const float* Pr = P[half];
#pragma unroll
  for (int i = 0; i < 8; ++i) {
    float o[8];
#pragma unroll
    for (int q = 0; q < 8; ++q) o[q] = 0.f;
#pragma unroll
    for (int j = 0; j < 8; ++j) {
      float pij = Pr[i * 8 + j];
#pragma unroll
      for (int q = 0; q < 8; ++q) o[q] += pij * hv[j][q];
    }
    short8 ov;
#pragma unroll
    for (int q = 0; q < 8; ++q) ov[q] = (short)f2bf(o[q]);
    *(short8*)(xx + (size_t)i * sOutE + wbase) = ov;
  }
}

// ---------------------------------------------------------------------------
// mix_head: fused second mix + policy/value heads.  2 batch rows per block.
// out: mu = out[bg*8+o] (o<8), values = out[Btot*8+bg].
// ---------------------------------------------------------------------------
__global__ __launch_bounds__(256)
void mix_head_kernel(const us* __restrict__ he, const float* __restrict__ probs_l,
                     const us* __restrict__ Wh, const float* __restrict__ ab,
                     const float* __restrict__ cb, float* __restrict__ out,
                     int b0, int chunkB, int Btot)
{
  const int r0 = blockIdx.x * 2;            // local row pair
  const int t = threadIdx.x;
  const int lane = t & 63;
  const int wave = t >> 6;
  __shared__ float P[2][64];
  __shared__ float red[2][9][4];
  if (t < 128)
    P[t >> 6][t & 63] = probs_l[(size_t)(b0 + r0 + (t >> 6)) * 64 + (t & 63)];
  __syncthreads();

  const size_t es = (size_t)chunkB * 1024;
  float xv[2][8][4];
#pragma unroll
  for (int r = 0; r < 2; ++r) {
#pragma unroll
    for (int i = 0; i < 8; ++i)
#pragma unroll
      for (int q = 0; q < 4; ++q) xv[r][i][q] = 0.f;
    const size_t rbase = (size_t)(r0 + r) * 1024 + (size_t)t * 4;
#pragma unroll
    for (int j = 0; j < 8; ++j) {
      ushort4 h4 = *(const ushort4*)(he + (size_t)j * es + rbase);
      float h0 = bf2f(h4.x), h1 = bf2f(h4.y), h2 = bf2f(h4.z), h3 = bf2f(h4.w);
#pragma unroll
      for (int i = 0; i < 8; ++i) {
        float p = P[r][i * 8 + j];
        xv[r][i][0] += p * h0; xv[r][i][1] += p * h1;
        xv[r][i][2] += p * h2; xv[r][i][3] += p * h3;
      }
    }
  }

  // head: s[r][o] = sum_{i,q} xv[r][i][q] * Wh[o][i*1024 + t*4 + q]
  float s[2][9];
#pragma unroll
  for (int o = 0; o < 9; ++o) { s[0][o] = 0.f; s[1][o] = 0.f; }
#pragma unroll
  for (int o = 0; o < 9; ++o) {
    const us* w = Wh + (size_t)o * 8192 + (size_t)t * 4;
#pragma unroll
    for (int i = 0; i < 8; ++i) {
      ushort4 w4 = *(const ushort4*)(w + i * 1024);
      float w0 = bf2f(w4.x), w1 = bf2f(w4.y), w2 = bf2f(w4.z), w3 = bf2f(w4.w);
      s[0][o] += xv[0][i][0]*w0 + xv[0][i][1]*w1 + xv[0][i][2]*w2 + xv[0][i][3]*w3;
      s[1][o] += xv[1][i][0]*w0 + xv[1][i][1]*w1 + xv[1][i][2]*w2 + xv[1][i][3]*w3;
    }
  }

  // wave shuffle-reduce (64-wide), then cross-wave via LDS
#pragma unroll
  for (int off = 32; off >= 1; off >>= 1) {
#pragma unroll
    for (int r = 0; r < 2; ++r)
#pragma unroll
      for (int o = 0; o < 9; ++o) s[r][o] += __shfl_down(s[r][o], off);
  }
  if (lane == 0) {
#pragma unroll
    for (int r = 0; r < 2; ++r)
#pragma unroll
      for (int o = 0; o < 9; ++o) red[r][o][wave] = s[r][o];
  }
  __syncthreads();
  if (t < 18) {
    int r = t / 9, o = t - r * 9;
    float v = red[r][o][0] + red[r][o][1] + red[r][o][2] + red[r][o][3];
    float bias = 0.f;
    if (o < 8) { for (int e = 0; e < 8; ++e) bias += ab[e * 8 + o]; }
    else       { for (int e = 0; e < 8; ++e) bias += cb[e]; }
    int bg = b0 + r0 + r;
    if (o < 8) out[(size_t)bg * 8 + o] = v + bias;
    else       out[(size_t)Btot * 8 + bg] = v + bias;
  }
}

// ---------------------------------------------------------------------------
extern "C" void kernel_launch(void* const* d_in, const int* in_sizes, int n_in,
                              void* d_out, int out_size, void* d_ws, size_t ws_size,
                              hipStream_t stream)
{
  const float* x   = (const float*)d_in[0];
  const float* sW1 = (const float*)d_in[1];
  const float* sb1 = (const float*)d_in[2];
  const float* sW2 = (const float*)d_in[3];
  const float* sb2 = (const float*)d_in[4];
  const float* sW3 = (const float*)d_in[5];
  const float* sb3 = (const float*)d_in[6];
  const float* tW  = (const float*)d_in[7];
  const float* tb  = (const float*)d_in[8];
  const float* rdW = (const float*)d_in[9];
  const float* rdb = (const float*)d_in[10];
  const float* ruW = (const float*)d_in[11];
  const float* rub = (const float*)d_in[12];
  const float* eW  = (const float*)d_in[13];
  const float* eb  = (const float*)d_in[14];
  const float* aW  = (const float*)d_in[15];
  const float* ab  = (const float*)d_in[16];
  const float* cW  = (const float*)d_in[17];
  const float* cb  = (const float*)d_in[18];
  float* out = (float*)d_out;

  const int B = 8192;
  const size_t BD = (size_t)B * 1024;
  char* ws = (char*)d_ws;

  // ---- arena: persistent region -------------------------------------------
  size_t o = 0;
  auto take = [&](size_t bytes) { size_t r = o; o = (o + bytes + 255) & ~(size_t)255; return r; };
  const size_t off_s1t  = take((size_t)512 * 128 * 2);
  const size_t off_s2t  = take((size_t)512 * 512 * 2);
  const size_t off_s3t  = take((size_t)1024 * 512 * 2);
  const size_t off_tWt  = take((size_t)1024 * 64 * 2);
  const size_t off_rdt  = take((size_t)2 * 64 * 1024 * 2);
  const size_t off_rut  = take((size_t)1024 * 64 * 2);
  const size_t off_eWt  = take((size_t)16 * 1024 * 1024 * 2);
  const size_t off_fobs = take(BD * 2);
  const size_t off_probs= take((size_t)2 * B * 64 * 4);
  const size_t off_Wh   = take((size_t)9 * 8192 * 2);
  const size_t P0 = o;
  // ---- scratch overlays (routing phase) -----------------------------------
  const size_t off_rin  = P0;                 // also h1
  const size_t off_rbuf = off_rin + BD * 2;   // also h2, u
  const size_t off_pbuf = off_rbuf + BD * 2;  // 8 split-K planes (4/layer)
  const size_t off_pbf  = off_pbuf + (size_t)8 * B * 64 * 4;
  const size_t off_obs  = off_pbf + (size_t)B * 64 * 2;
  const size_t off_task = off_obs + (size_t)B * 128 * 2;
  const size_t routing_end = off_task + (size_t)B * 64 * 2;

  // ---- expert-stage chunk selection (he/xx overlay scratch at P0) ---------
  // Prefer 4096: he+xx (134MB) + eWt (32MB) Infinity-Cache-resident, and
  // only +4 launches vs the monolithic 8192 config (R15's 2048 was +12).
  int chunk = 0;
  const int cands[4] = {4096, 2048, 1024, 512};
  for (int i = 0; i < 4; ++i) {
    size_t need = P0 + (size_t)cands[i] * 32768;  // he + xx
    if (need <= ws_size) { chunk = cands[i]; break; }
  }
  if (!chunk || routing_end > ws_size) return;

  us* s1t  = (us*)(ws + off_s1t);
  us* s2t  = (us*)(ws + off_s2t);
  us* s3t  = (us*)(ws + off_s3t);
  us* tWt  = (us*)(ws + off_tWt);
  us* rdt  = (us*)(ws + off_rdt);
  us* rut  = (us*)(ws + off_rut);
  us* eWt  = (us*)(ws + off_eWt);
  us* fobs = (us*)(ws + off_fobs);
  float* probs = (float*)(ws + off_probs);
  us* Wh   = (us*)(ws + off_Wh);
  us* rin  = (us*)(ws + off_rin);
  us* rbuf = (us*)(ws + off_rbuf);
  float* pbuf = (float*)(ws + off_pbuf);
  us* pbf  = (us*)(ws + off_pbf);
  us* obs_bf  = (us*)(ws + off_obs);
  us* task_bf = (us*)(ws + off_task);
  us* h1 = rin;
  us* h2 = rbuf;
  us* he = (us*)(ws + P0);
  us* xx = (us*)(ws + P0 + (size_t)chunk * 16384);

  // ---- fused prep: transposes + Wh + x split ------------------------------
  prep_kernel<<<dim3(23904), 256, 0, stream>>>(x, sW1, sW2, sW3, tW, rdW, ruW,
      eW, aW, cW, obs_bf, task_bf, s1t, s2t, s3t, tWt, rdt, rut, eWt, Wh);

  // ---- shared MLP ---------------------------------------------------------
  gemm_main<true, true, false, false, false><<<dim3(4, 64, 1), 256, 0, stream>>>(
      obs_bf, s1t, sb1, h1, (us*)0, (const us*)0, 512, 128, 128, 128, 0, 0, 0, 0);
  gemm_main<true, true, false, false, false><<<dim3(4, 64, 1), 256, 0, stream>>>(
      h1, s2t, sb2, h2, (us*)0, (const us*)0, 512, 512, 512, 512, 0, 0, 0, 0);
  gemm_main<true, false, false, false, false><<<dim3(8, 64, 1), 256, 0, stream>>>(
      h2, s3t, sb3, fobs, (us*)0, (const us*)0, 1024, 512, 512, 512, 0, 0, 0, 0);
  // z-GEMM fused: rin = relu(task@tW+tb)*fobs ; rbuf = relu(rin)
  gemm_main<true, true, true, false, true><<<dim3(8, 64, 1), 256, 0, stream>>>(
      task_bf, tWt, tb, rin, rbuf, fobs, 1024, 64, 64, 64, 0, 0, 0, 0);

  // ---- routing (layers 0,1; layer 2 is dead code) -------------------------
  gemm_splitk<<<dim3(1, 64, 4), 256, 0, stream>>>(rbuf, rdt, pbuf,
      64, 256, 1024, 1024, 256, 256);                                // p0
  mk_pbf<<<dim3((B * 64 + 255) / 256), 256, 0, stream>>>(pbuf, rdb, pbf, B * 64);
  // u-GEMM fused: rbuf = relu((pbf@ruW+rub) * rin)
  gemm_main<true, false, true, true, false><<<dim3(8, 64, 1), 256, 0, stream>>>(
      pbf, rut, rub, rbuf, (us*)0, rin, 1024, 64, 64, 64, 0, 0, 0, 0);
  gemm_splitk<<<dim3(1, 64, 4), 256, 0, stream>>>(rbuf, rdt + 65536,
      pbuf + (size_t)4 * B * 64, 64, 256, 1024, 1024, 256, 256);     // p1
  softmax8_kernel<<<dim3((2 * B * 8 + 255) / 256), 256, 0, stream>>>(
      pbuf, probs, rdb, B * 8, 2 * B * 8, (long long)B * 64);

  // ---- expert stage, chunked over batch (L3-resident at chunk=4096) -------
  const long long sHE = (long long)chunk * 1024;
  for (int b0 = 0; b0 < B; b0 += chunk) {
    gemm_n256<true, true><<<dim3(4, chunk / 256, 8), 512, 0, stream>>>(
        fobs + (size_t)b0 * 1024, eWt, eb, he,
        1024, 1024, 1024, 1024, 0, 1048576, 1024, sHE);
    mix_kernel<<<dim3(chunk / 2), 256, 0, stream>>>(he, probs, xx, b0, chunk, sHE, 1024);
    gemm_n256<true, true><<<dim3(4, chunk / 256, 8), 512, 0, stream>>>(
        xx, eWt + (size_t)8 * 1048576, eb + 8192, he,
        1024, 1024, 1024, 1024, sHE, 1048576, 1024, sHE);
    // fused second mix + heads: no xx b-major materialization, no atomics
    mix_head_kernel<<<dim3(chunk / 2), 256, 0, stream>>>(
        he, probs + (size_t)B * 64, Wh, ab, cb, out, b0, chunk, B);
  }
}